// Round 4
// baseline (155.510 us; speedup 1.0000x reference)
//
#include <hip/hip_runtime.h>

#define BDIM 256
constexpr int Bn = 16, Cn = 4, Hn = 512, Wn = 512;
constexpr int BC = Bn * Cn;                  // 64 slices
constexpr float NTOT = 16777216.0f;          // B*C*H*W
constexpr int GPS = Hn * Wn / 4;             // float4/int4 groups per slice = 65536
constexpr int BPS = 32;                      // blocks per slice
constexpr int ROWS = 16;                     // rows per block
constexpr int GPR = Wn / 4;                  // 128 groups per row
constexpr int GPB = ROWS * GPR;              // 2048 groups per block
constexpr int ITERS = GPB / BDIM;            // 8
constexpr int NBLK = BC * BPS;               // 2048 blocks = exactly 8 per CU
constexpr float SMOOTHF = 0.0001f;

__device__ __forceinline__ float wave_reduce(float v) {
#pragma unroll
    for (int off = 32; off > 0; off >>= 1) v += __shfl_down(v, off);
    return v;
}

// 2048 blocks x 256 thr; __launch_bounds__(256,8): budget 64 VGPR so the
// scheduler does NOT sink the prefetch loads (R2 regression: VGPR=28 proved
// the 8 float4 prefetches were serialized to their use points).
__global__ __launch_bounds__(BDIM, 8) void seg_main(const float4* __restrict__ cmap,
                                                    const int4* __restrict__ gt,
                                                    float* __restrict__ ws) {
    __shared__ unsigned int lg[(ROWS + 2) * GPR];   // 18 rows x 128 packed uints
    __shared__ float sm[5][4];

    const int tid   = threadIdx.x;
    const int slice = blockIdx.x >> 5;
    const int bis   = blockIdx.x & 31;
    const int R0    = bis * ROWS;
    const int colg  = tid & 127;
    const int rhalf = tid >> 7;                  // 0 or 1

    const float4* xp = cmap + slice * GPS + R0 * GPR + tid;

    float4 xr[ITERS];
    // ---- first half of cmap prefetch; pin above staging ----
    xr[0] = xp[0 * BDIM];
    xr[1] = xp[1 * BDIM];
    xr[2] = xp[2 * BDIM];
    xr[3] = xp[3 * BDIM];
    __builtin_amdgcn_sched_barrier(0);

    // ---- stage gt rows R0-1 .. R0+16 into LDS, packed 4 bytes/uint ----
    // Branchless: clamp the row, load unconditionally, select 0 for pad rows.
    const int4* gslice = gt + slice * GPS;
#pragma unroll
    for (int i = 0; i < 9; ++i) {
        const int e  = tid + i * BDIM;           // 0..2303
        const int sr = e >> 7;                   // staged row 0..17
        const int cg = e & 127;
        const int gr = R0 - 1 + sr;              // global row (may be -1 or 512)
        const int grc = min(max(gr, 0), Hn - 1);
        const int4 c = gslice[grc * GPR + cg];
        unsigned int v = (unsigned)c.x | ((unsigned)c.y << 8) |
                         ((unsigned)c.z << 16) | ((unsigned)c.w << 24);
        if (gr < 0 || gr >= Hn) v = 0u;
        lg[e] = v;
    }

    // ---- second half of cmap prefetch: issue BEFORE the barrier so the
    //      loads are in flight across the barrier wait ----
    xr[4] = xp[4 * BDIM];
    xr[5] = xp[5 * BDIM];
    xr[6] = xp[6 * BDIM];
    xr[7] = xp[7 * BDIM];
    __builtin_amdgcn_sched_barrier(0);
    __syncthreads();

    float cesum = 0.f, cxy = 0.f, ed = 0.f, inter = 0.f, jsum = 0.f;
    int icnt = 0;
    const int lbase = (rhalf + 1) * GPR + colg;

#pragma unroll
    for (int it = 0; it < ITERS; ++it) {
        const int li = lbase + it * 2 * GPR;     // center word in staged LDS

        const unsigned cu = lg[li];
        const unsigned uu = lg[li - GPR];
        const unsigned du = lg[li + GPR];
        unsigned pv = lg[li - (colg > 0 ? 1 : 0)];
        unsigned nx = lg[li + (colg < 127 ? 1 : 0)];
        if (colg == 0)   pv = 0u;
        if (colg == 127) nx = 0u;

        const unsigned lu = (cu << 8) | (pv >> 24);
        const unsigned ru = (cu >> 8) | (nx << 24);
        const unsigned s  = cu + uu + du + lu + ru;  // byte-wise sums, max 5

        icnt += __popc(cu);                      // bytes are 0/1

        const float4 x = xr[it];
        const float xs[4] = {x.x, x.y, x.z, x.w};

#pragma unroll
        for (int e = 0; e < 4; ++e) {
            const float xv = xs[e];
            const float t  = __expf(-fabsf(xv));            // exp(-|x|)
            const float u1 = 1.f + t;
            const float sp = fmaxf(xv, 0.f) + __logf(u1);   // softplus = logaddexp(0,x)
            const float r1 = __builtin_amdgcn_rcpf(u1);
            const float pred = (xv >= 0.f) ? r1 : t * r1;   // sigmoid(x)

            cesum += sp;
            const unsigned yb = (cu >> (8 * e)) & 1u;
            const unsigned sb = (s  >> (8 * e)) & 0xffu;
            if (yb) { cxy += xv; inter += pred; }           // cndmask-predicated
            if (sb - 1u < 4u) ed += fminf(sp, 100.f);       // edge <=> 1<=s<=4
            jsum += pred;
        }
    }

    // ---- block reduction, one write per partial, no atomics ----
    const int wave = tid >> 6, lane = tid & 63;
    const float v0 = wave_reduce(cesum - cxy);
    const float v1 = wave_reduce(ed);
    const float v2 = wave_reduce(inter);
    const float v3 = wave_reduce((float)icnt);
    const float v4 = wave_reduce(jsum);
    if (lane == 0) {
        sm[0][wave] = v0; sm[1][wave] = v1; sm[2][wave] = v2;
        sm[3][wave] = v3; sm[4][wave] = v4;
    }
    __syncthreads();
    if (tid < 5)
        ws[tid * NBLK + blockIdx.x] = sm[tid][0] + sm[tid][1] + sm[tid][2] + sm[tid][3];
}

__global__ void seg_finish(const float* __restrict__ ws, float* __restrict__ out) {
    const int t = threadIdx.x;                   // 64 threads, one per (b,c) slice
    float ce = 0.f, ed = 0.f, inter = 0.f, is = 0.f, js = 0.f;
#pragma unroll 4
    for (int i = 0; i < BPS; ++i) {
        const int b = t * BPS + i;
        ce    += ws[0 * NBLK + b];
        ed    += ws[1 * NBLK + b];
        inter += ws[2 * NBLK + b];
        is    += ws[3 * NBLK + b];
        js    += ws[4 * NBLK + b];
    }
    const float score = (2.f * inter + SMOOTHF) / (is + js + SMOOTHF);
    float dice = (1.f - score) * (1.f / (float)Bn);   // mean over batch
    dice = wave_reduce(dice);                         // sum over classes (64 slices)
    ce = wave_reduce(ce);
    ed = wave_reduce(ed);
    if (t == 0)
        out[0] = ce * (1.f / NTOT) + ed * (1.f / NTOT) + dice;
}

extern "C" void kernel_launch(void* const* d_in, const int* in_sizes, int n_in,
                              void* d_out, int out_size, void* d_ws, size_t ws_size,
                              hipStream_t stream) {
    const float4* cmap = (const float4*)d_in[0];
    const int4*   gt   = (const int4*)d_in[1];
    float* ws = (float*)d_ws;                     // 5 * 2048 floats, fully rewritten
    seg_main<<<NBLK, BDIM, 0, stream>>>(cmap, gt, ws);
    seg_finish<<<1, 64, 0, stream>>>(ws, (float*)d_out);
}

// Round 5
// 146.724 us; speedup vs baseline: 1.0599x; 1.0599x over previous
//
#include <hip/hip_runtime.h>

#define BDIM 256
constexpr int Bn = 16, Cn = 4, Hn = 512, Wn = 512;
constexpr int BC = Bn * Cn;                  // 64 slices
constexpr float NTOT = 16777216.0f;          // B*C*H*W
constexpr int GPS = Hn * Wn / 4;             // float4/int4 groups per slice = 65536
constexpr int BPS = 32;                      // blocks per slice
constexpr int ROWS = 16;                     // rows per block
constexpr int GPR = Wn / 4;                  // 128 groups per row
constexpr int GPB = ROWS * GPR;              // 2048 groups per block
constexpr int ITERS = GPB / BDIM;            // 8
constexpr int NBLK = BC * BPS;               // 2048 blocks = 8 per CU
constexpr float SMOOTHF = 0.0001f;

__device__ __forceinline__ float wave_reduce(float v) {
#pragma unroll
    for (int off = 32; off > 0; off >>= 1) v += __shfl_down(v, off);
    return v;
}

// Async global->LDS DMA, 16B per lane. No VGPR return, deep vmcnt queue:
// this is the only load path the compiler cannot serialize down to MLP=1.
__device__ __forceinline__ void gload_lds16(const void* g, void* l) {
    __builtin_amdgcn_global_load_lds(
        (const __attribute__((address_space(1))) void*)g,
        (__attribute__((address_space(3))) void*)l, 16, 0, 0);
}

// 42 KB LDS/block -> 3 blocks/CU. Block in barrier-drain overlaps with the
// other two computing (m97-style structural overlap).
__global__ __launch_bounds__(BDIM, 3) void seg_main(const float4* __restrict__ cmap,
                                                    const int4* __restrict__ gt,
                                                    float* __restrict__ ws) {
    __shared__ float4 lx[GPB];                      // 32 KB staged cmap tile
    __shared__ unsigned int lg[(ROWS + 2) * GPR];   // 9.2 KB packed gt (18 rows halo)
    __shared__ float sm[5][4];

    const int tid   = threadIdx.x;
    const int slice = blockIdx.x >> 5;
    const int bis   = blockIdx.x & 31;
    const int R0    = bis * ROWS;
    const int colg  = tid & 127;
    const int rhalf = tid >> 7;                  // 0 or 1

    // ---- issue cmap tile DMA: 8 x 16B per thread, linear layout.
    // Wave-uniform base + lane*16: LDS dst offset == global offset (both linear).
    const float4* xp = cmap + slice * GPS + R0 * GPR + tid;
#pragma unroll
    for (int i = 0; i < ITERS; ++i)
        gload_lds16((const void*)(xp + i * BDIM), (void*)(lx + tid + i * BDIM));

    // ---- stage gt rows R0-1 .. R0+16 into LDS, packed 4 bytes/uint ----
    const int4* gslice = gt + slice * GPS;
#pragma unroll
    for (int i = 0; i < 9; ++i) {
        const int e  = tid + i * BDIM;           // 0..2303
        const int sr = e >> 7;                   // staged row 0..17
        const int cg = e & 127;
        const int gr = R0 - 1 + sr;              // global row (may be -1 or 512)
        const int grc = min(max(gr, 0), Hn - 1);
        const int4 c = gslice[grc * GPR + cg];
        unsigned int v = (unsigned)c.x | ((unsigned)c.y << 8) |
                         ((unsigned)c.z << 16) | ((unsigned)c.w << 24);
        if (gr < 0 || gr >= Hn) v = 0u;
        lg[e] = v;
    }
    __syncthreads();                             // drains DMA vmcnt too

    float cesum = 0.f, cxy = 0.f, ed = 0.f, inter = 0.f, jsum = 0.f;
    int icnt = 0;
    const int lbase = (rhalf + 1) * GPR + colg;

#pragma unroll
    for (int it = 0; it < ITERS; ++it) {
        const int li = lbase + it * 2 * GPR;     // center word in staged gt

        const unsigned cu = lg[li];
        const unsigned uu = lg[li - GPR];
        const unsigned du = lg[li + GPR];
        unsigned pv = lg[li - (colg > 0 ? 1 : 0)];
        unsigned nx = lg[li + (colg < 127 ? 1 : 0)];
        if (colg == 0)   pv = 0u;
        if (colg == 127) nx = 0u;

        const unsigned lu = (cu << 8) | (pv >> 24);
        const unsigned ru = (cu >> 8) | (nx << 24);
        const unsigned s  = cu + uu + du + lu + ru;  // byte-wise sums, max 5

        icnt += __popc(cu);                      // bytes are 0/1

        const float4 x = lx[it * BDIM + tid];    // ds_read_b128, conflict-free
        const float xs[4] = {x.x, x.y, x.z, x.w};

#pragma unroll
        for (int e = 0; e < 4; ++e) {
            const float xv = xs[e];
            const float t  = __expf(-fabsf(xv));            // exp(-|x|)
            const float u1 = 1.f + t;
            const float sp = fmaxf(xv, 0.f) + __logf(u1);   // softplus = logaddexp(0,x)
            const float r1 = __builtin_amdgcn_rcpf(u1);
            const float pred = (xv >= 0.f) ? r1 : t * r1;   // sigmoid(x)
            const float yf = (float)((cu >> (8 * e)) & 1u); // bfe + cvt

            cesum += sp;
            cxy   = fmaf(yf, xv, cxy);                      // ce = cesum - cxy
            inter = fmaf(yf, pred, inter);
            jsum += pred;
            const unsigned sb = (s >> (8 * e)) & 0xffu;
            if (sb - 1u < 4u) ed += fminf(sp, 100.f);       // edge <=> 1<=s<=4
        }
    }

    // ---- block reduction, one write per partial, no atomics ----
    const int wave = tid >> 6, lane = tid & 63;
    const float v0 = wave_reduce(cesum - cxy);
    const float v1 = wave_reduce(ed);
    const float v2 = wave_reduce(inter);
    const float v3 = wave_reduce((float)icnt);
    const float v4 = wave_reduce(jsum);
    if (lane == 0) {
        sm[0][wave] = v0; sm[1][wave] = v1; sm[2][wave] = v2;
        sm[3][wave] = v3; sm[4][wave] = v4;
    }
    __syncthreads();
    if (tid < 5)
        ws[tid * NBLK + blockIdx.x] = sm[tid][0] + sm[tid][1] + sm[tid][2] + sm[tid][3];
}

__global__ void seg_finish(const float* __restrict__ ws, float* __restrict__ out) {
    const int t = threadIdx.x;                   // 64 threads, one per (b,c) slice
    float ce = 0.f, ed = 0.f, inter = 0.f, is = 0.f, js = 0.f;
#pragma unroll 4
    for (int i = 0; i < BPS; ++i) {
        const int b = t * BPS + i;
        ce    += ws[0 * NBLK + b];
        ed    += ws[1 * NBLK + b];
        inter += ws[2 * NBLK + b];
        is    += ws[3 * NBLK + b];
        js    += ws[4 * NBLK + b];
    }
    const float score = (2.f * inter + SMOOTHF) / (is + js + SMOOTHF);
    float dice = (1.f - score) * (1.f / (float)Bn);   // mean over batch
    dice = wave_reduce(dice);                         // sum over classes (64 slices)
    ce = wave_reduce(ce);
    ed = wave_reduce(ed);
    if (t == 0)
        out[0] = ce * (1.f / NTOT) + ed * (1.f / NTOT) + dice;
}

extern "C" void kernel_launch(void* const* d_in, const int* in_sizes, int n_in,
                              void* d_out, int out_size, void* d_ws, size_t ws_size,
                              hipStream_t stream) {
    const float4* cmap = (const float4*)d_in[0];
    const int4*   gt   = (const int4*)d_in[1];
    float* ws = (float*)d_ws;                     // 5 * 2048 floats, fully rewritten
    seg_main<<<NBLK, BDIM, 0, stream>>>(cmap, gt, ws);
    seg_finish<<<1, 64, 0, stream>>>(ws, (float*)d_out);
}